// Round 1
// baseline (410.621 us; speedup 1.0000x reference)
//
#include <hip/hip_runtime.h>
#include <hip/hip_bf16.h>
#include <math.h>

#define B_DIM   4096
#define IN_DIM  4096
#define OUT_DIM 4096

typedef __attribute__((ext_vector_type(8))) short  short8;   // 8 x bf16 = 4 VGPRs
typedef __attribute__((ext_vector_type(4))) float  floatx4;  // MFMA 16x16 accum

// ---------------- fp32 -> bf16 (round-to-nearest-even) ----------------
__global__ void cvt_bf16(const float* __restrict__ in, ushort* __restrict__ out, int n) {
    int i = (blockIdx.x * blockDim.x + threadIdx.x) * 4;
    const int stride = gridDim.x * blockDim.x * 4;
    for (; i < n; i += stride) {
        float4 v = *(const float4*)(in + i);
        ushort4 o;
        unsigned b;
        b = __float_as_uint(v.x); o.x = (ushort)((b + 0x7fffu + ((b >> 16) & 1u)) >> 16);
        b = __float_as_uint(v.y); o.y = (ushort)((b + 0x7fffu + ((b >> 16) & 1u)) >> 16);
        b = __float_as_uint(v.z); o.z = (ushort)((b + 0x7fffu + ((b >> 16) & 1u)) >> 16);
        b = __float_as_uint(v.w); o.w = (ushort)((b + 0x7fffu + ((b >> 16) & 1u)) >> 16);
        *(ushort4*)(out + i) = o;
    }
}

// ---------------- stage A: partial column sums of x (fp64) ----------------
// grid (16, 32): blockIdx.x -> 256-col slab, blockIdx.y -> 128-row chunk
__global__ void colsum_partial(const float* __restrict__ x, double* __restrict__ part) {
    int col = blockIdx.x * 256 + threadIdx.x;
    int r0  = blockIdx.y * 128;
    const float* p = x + (size_t)r0 * IN_DIM + col;
    double s = 0.0;
    for (int r = 0; r < 128; ++r) s += (double)p[(size_t)r * IN_DIM];
    part[blockIdx.y * IN_DIM + col] = s;
}

// ---------------- stage B: fold partials -> xbar = mean(x, axis=0) ----------------
__global__ void xbar_reduce(const double* __restrict__ part, double* __restrict__ xbar) {
    int i = blockIdx.x * 256 + threadIdx.x;
    double s = 0.0;
    for (int rb = 0; rb < 32; ++rb) s += part[rb * IN_DIM + i];
    xbar[i] = s * (1.0 / (double)B_DIM);
}

// ---------------- means[o] = dot(xbar, W[o,:]) + b[o]  ->  idx[o] ----------------
__global__ void means_idx(const float* __restrict__ W, const float* __restrict__ bias,
                          const double* __restrict__ xbar, int* __restrict__ idx) {
    __shared__ double red[256];
    int o = blockIdx.x;
    const float* wr = W + (size_t)o * IN_DIM;
    double s = 0.0;
    for (int i = threadIdx.x; i < IN_DIM; i += 256)
        s += (double)wr[i] * xbar[i];
    red[threadIdx.x] = s;
    __syncthreads();
    for (int st = 128; st > 0; st >>= 1) {
        if (threadIdx.x < st) red[threadIdx.x] += red[threadIdx.x + st];
        __syncthreads();
    }
    if (threadIdx.x == 0) {
        // mimic jnp fp32 mod semantics (incl. md==3.0f edge -> else-branch/sigmoid)
        float mf = (float)(red[0] + (double)bias[o]);
        float md = fmodf(mf, 3.0f);
        if (md < 0.0f) md += 3.0f;
        idx[o] = (int)md;
    }
}

// ---------------- bf16 MFMA GEMM (Bt layout) + fused bias/activation ----------------
// 128x128 block tile, BK=32, 256 threads = 4 waves in 2x2, each wave 64x64 (4x4 MFMAs)
__global__ void __launch_bounds__(256) gemm_bt_act(
    const ushort* __restrict__ A,   // [M,K] bf16 bits (x)
    const ushort* __restrict__ Bt,  // [N,K] bf16 bits (W)
    const float*  __restrict__ bias,
    const int*    __restrict__ idx,
    float*        __restrict__ out) {
    __shared__ __align__(16) ushort As[128 * 32];
    __shared__ __align__(16) ushort Bs[128 * 32];

    const int t    = threadIdx.x;
    const int w    = t >> 6;
    const int l    = t & 63;
    const int quad = l >> 4;
    const int lrow = l & 15;
    const int m0   = blockIdx.y * 128;
    const int n0   = blockIdx.x * 128;
    const int m0w  = (w >> 1) * 64;
    const int n0w  = (w & 1) * 64;
    const int K    = IN_DIM;

    floatx4 acc[4][4] = {};

    for (int k0 = 0; k0 < K; k0 += 32) {
        // stage 128x32 bf16 A-tile and B-tile via direct-to-LDS (16B/lane)
#pragma unroll
        for (int j = 0; j < 2; ++j) {
            int chunk  = j * 256 + t;
            int r      = chunk >> 2;          // tile row 0..127
            int kc     = (chunk & 3) << 3;    // k sub-chunk 0,8,16,24
            int ldsoff = (j * 256 + w * 64) * 8;  // wave-uniform base (elements)
            __builtin_amdgcn_global_load_lds(
                (__attribute__((address_space(1))) void*)(A + (size_t)(m0 + r) * K + k0 + kc),
                (__attribute__((address_space(3))) void*)(As + ldsoff), 16, 0, 0);
            __builtin_amdgcn_global_load_lds(
                (__attribute__((address_space(1))) void*)(Bt + (size_t)(n0 + r) * K + k0 + kc),
                (__attribute__((address_space(3))) void*)(Bs + ldsoff), 16, 0, 0);
        }
        __syncthreads();

        short8 af[4], bf[4];
#pragma unroll
        for (int mi = 0; mi < 4; ++mi)
            af[mi] = *(const short8*)&As[(m0w + mi * 16 + lrow) * 32 + quad * 8];
#pragma unroll
        for (int ni = 0; ni < 4; ++ni)
            bf[ni] = *(const short8*)&Bs[(n0w + ni * 16 + lrow) * 32 + quad * 8];

#pragma unroll
        for (int mi = 0; mi < 4; ++mi)
#pragma unroll
            for (int ni = 0; ni < 4; ++ni)
                acc[mi][ni] = __builtin_amdgcn_mfma_f32_16x16x32_bf16(
                    af[mi], bf[ni], acc[mi][ni], 0, 0, 0);
        __syncthreads();
    }

    // epilogue: y = acc + bias[col]; activation by idx[col]
    // C/D mapping (verified): col = lane&15, row = quad*4 + reg
#pragma unroll
    for (int ni = 0; ni < 4; ++ni) {
        int   col = n0 + n0w + ni * 16 + lrow;
        int   id  = idx[col];
        float bv  = bias[col];
#pragma unroll
        for (int mi = 0; mi < 4; ++mi) {
            int rowb = m0 + m0w + mi * 16 + quad * 4;
#pragma unroll
            for (int r = 0; r < 4; ++r) {
                float y = acc[mi][ni][r] + bv;
                float v;
                if (id == 0)      v = fmaxf(y, 0.0f);
                else if (id == 1) v = tanhf(y);
                else              v = 1.0f / (1.0f + __expf(-y));
                out[(size_t)(rowb + r) * OUT_DIM + col] = v;
            }
        }
    }
}

extern "C" void kernel_launch(void* const* d_in, const int* in_sizes, int n_in,
                              void* d_out, int out_size, void* d_ws, size_t ws_size,
                              hipStream_t stream) {
    const float* x = (const float*)d_in[0];
    const float* W = (const float*)d_in[1];
    const float* b = (const float*)d_in[2];
    float* out = (float*)d_out;

    char* ws = (char*)d_ws;
    ushort* xb   = (ushort*)(ws);                      // 33554432 B
    ushort* wb   = (ushort*)(ws + 33554432);           // 33554432 B
    double* part = (double*)(ws + 67108864);           // 32*4096*8 = 1 MB
    double* xbar = (double*)(ws + 68157440);           // 32 KB
    int*    idx  = (int*)   (ws + 68190208);           // 16 KB

    cvt_bf16<<<2048, 256, 0, stream>>>(x, xb, B_DIM * IN_DIM);
    cvt_bf16<<<2048, 256, 0, stream>>>(W, wb, OUT_DIM * IN_DIM);
    colsum_partial<<<dim3(16, 32), 256, 0, stream>>>(x, part);
    xbar_reduce<<<16, 256, 0, stream>>>(part, xbar);
    means_idx<<<4096, 256, 0, stream>>>(W, b, xbar, idx);
    gemm_bt_act<<<dim3(32, 32), 256, 0, stream>>>(xb, wb, b, idx, out);
}

// Round 2
// 365.790 us; speedup vs baseline: 1.1226x; 1.1226x over previous
//
#include <hip/hip_runtime.h>
#include <hip/hip_bf16.h>
#include <math.h>

#define B_DIM   4096
#define IN_DIM  4096
#define OUT_DIM 4096

typedef __attribute__((ext_vector_type(8))) short  short8;   // 8 x bf16 = 4 VGPRs
typedef __attribute__((ext_vector_type(4))) float  floatx4;  // MFMA 16x16 accum

__device__ __forceinline__ ushort f2bf(float f) {
    unsigned b = __float_as_uint(f);
    return (ushort)((b + 0x7fffu + ((b >> 16) & 1u)) >> 16);   // RNE
}

// ---- fused: x fp32 -> bf16  AND  fp64 partial column sums of x ----
// grid (4, 256): bx -> 1024-col slab (4 cols/thread), by -> 16-row chunk
__global__ void cvt_x_colsum(const float* __restrict__ x, ushort* __restrict__ xb,
                             double* __restrict__ part) {
    int c0 = blockIdx.x * 1024 + threadIdx.x * 4;
    int r0 = blockIdx.y * 16;
    double s0 = 0, s1 = 0, s2 = 0, s3 = 0;
#pragma unroll 4
    for (int r = 0; r < 16; ++r) {
        size_t off = (size_t)(r0 + r) * IN_DIM + c0;
        float4 v = *(const float4*)(x + off);
        ushort4 o;
        o.x = f2bf(v.x); o.y = f2bf(v.y); o.z = f2bf(v.z); o.w = f2bf(v.w);
        *(ushort4*)(xb + off) = o;
        s0 += (double)v.x; s1 += (double)v.y; s2 += (double)v.z; s3 += (double)v.w;
    }
    double* p = part + (size_t)blockIdx.y * IN_DIM + c0;
    p[0] = s0; p[1] = s1; p[2] = s2; p[3] = s3;
}

// ---- fold 256 partial chunks -> xbar = mean(x, axis=0) (fp64) ----
__global__ void xbar_reduce(const double* __restrict__ part, double* __restrict__ xbar) {
    int i = blockIdx.x * 256 + threadIdx.x;
    double s = 0.0;
    for (int rb = 0; rb < 256; ++rb) s += part[(size_t)rb * IN_DIM + i];
    xbar[i] = s * (1.0 / (double)B_DIM);
}

// ---- fused: W fp32 -> bf16  AND  means[o] = dot(xbar,W[o,:]) + b[o] -> idx[o] ----
__global__ void cvt_w_means(const float* __restrict__ W, const float* __restrict__ bias,
                            const double* __restrict__ xbar, ushort* __restrict__ wb,
                            int* __restrict__ idx) {
    __shared__ double red[256];
    int o = blockIdx.x;
    size_t base = (size_t)o * IN_DIM;
    double s = 0.0;
#pragma unroll
    for (int j = 0; j < 4; ++j) {
        int i = j * 1024 + threadIdx.x * 4;
        float4 v = *(const float4*)(W + base + i);
        ushort4 ob;
        ob.x = f2bf(v.x); ob.y = f2bf(v.y); ob.z = f2bf(v.z); ob.w = f2bf(v.w);
        *(ushort4*)(wb + base + i) = ob;
        s += (double)v.x * xbar[i]     + (double)v.y * xbar[i + 1]
           + (double)v.z * xbar[i + 2] + (double)v.w * xbar[i + 3];
    }
    red[threadIdx.x] = s;
    __syncthreads();
    for (int st = 128; st > 0; st >>= 1) {
        if (threadIdx.x < st) red[threadIdx.x] += red[threadIdx.x + st];
        __syncthreads();
    }
    if (threadIdx.x == 0) {
        // fp32 mod semantics as in jnp (md==3.0f edge lands in else/sigmoid)
        float mf = (float)(red[0] + (double)bias[o]);
        float md = fmodf(mf, 3.0f);
        if (md < 0.0f) md += 3.0f;
        idx[o] = (int)md;
    }
}

// ---- bf16 MFMA GEMM (Bt layout) + fused branchless bias/activation ----
__global__ void __launch_bounds__(256) gemm_bt_act(
    const ushort* __restrict__ A,   // [M,K] bf16 bits (x)
    const ushort* __restrict__ Bt,  // [N,K] bf16 bits (W)
    const float*  __restrict__ bias,
    const int*    __restrict__ idx,
    float*        __restrict__ out) {
    __shared__ __align__(16) ushort As[128 * 32];
    __shared__ __align__(16) ushort Bs[128 * 32];

    const int t    = threadIdx.x;
    const int w    = t >> 6;
    const int l    = t & 63;
    const int quad = l >> 4;
    const int lrow = l & 15;
    const int m0   = blockIdx.y * 128;
    const int n0   = blockIdx.x * 128;
    const int m0w  = (w >> 1) * 64;
    const int n0w  = (w & 1) * 64;
    const int K    = IN_DIM;

    floatx4 acc[4][4] = {};

    for (int k0 = 0; k0 < K; k0 += 32) {
#pragma unroll
        for (int j = 0; j < 2; ++j) {
            int chunk  = j * 256 + t;
            int r      = chunk >> 2;          // tile row 0..127
            int kc     = (chunk & 3) << 3;    // k sub-chunk 0,8,16,24
            int ldsoff = (j * 256 + w * 64) * 8;  // wave-uniform base (elements)
            __builtin_amdgcn_global_load_lds(
                (__attribute__((address_space(1))) void*)(A + (size_t)(m0 + r) * K + k0 + kc),
                (__attribute__((address_space(3))) void*)(As + ldsoff), 16, 0, 0);
            __builtin_amdgcn_global_load_lds(
                (__attribute__((address_space(1))) void*)(Bt + (size_t)(n0 + r) * K + k0 + kc),
                (__attribute__((address_space(3))) void*)(Bs + ldsoff), 16, 0, 0);
        }
        __syncthreads();

        short8 af[4], bf[4];
#pragma unroll
        for (int mi = 0; mi < 4; ++mi)
            af[mi] = *(const short8*)&As[(m0w + mi * 16 + lrow) * 32 + quad * 8];
#pragma unroll
        for (int ni = 0; ni < 4; ++ni)
            bf[ni] = *(const short8*)&Bs[(n0w + ni * 16 + lrow) * 32 + quad * 8];

#pragma unroll
        for (int mi = 0; mi < 4; ++mi)
#pragma unroll
            for (int ni = 0; ni < 4; ++ni)
                acc[mi][ni] = __builtin_amdgcn_mfma_f32_16x16x32_bf16(
                    af[mi], bf[ni], acc[mi][ni], 0, 0, 0);
        __syncthreads();
    }

    // epilogue: y = acc + bias[col]; branchless activation by idx[col]
    // C/D mapping (verified): col = lane&15, row = quad*4 + reg
    // relu(y)=max(y,0); sigmoid(y)=rcp(1+exp(-y)); tanh(y)=2*sigmoid(2y)-1
#pragma unroll
    for (int ni = 0; ni < 4; ++ni) {
        int   col     = n0 + n0w + ni * 16 + lrow;
        int   id      = idx[col];
        float bv      = bias[col];
        float a       = (id == 1) ? -2.0f : -1.0f;
        bool  isrelu  = (id == 0);
        bool  istanh  = (id == 1);
#pragma unroll
        for (int mi = 0; mi < 4; ++mi) {
            int rowb = m0 + m0w + mi * 16 + quad * 4;
#pragma unroll
            for (int r = 0; r < 4; ++r) {
                float y   = acc[mi][ni][r] + bv;
                float e   = __expf(a * y);                     // v_exp_f32 path
                float s   = __builtin_amdgcn_rcpf(1.0f + e);   // v_rcp_f32
                float act = istanh ? fmaf(2.0f, s, -1.0f) : s;
                float v   = isrelu ? fmaxf(y, 0.0f) : act;
                out[(size_t)(rowb + r) * OUT_DIM + col] = v;
            }
        }
    }
}

extern "C" void kernel_launch(void* const* d_in, const int* in_sizes, int n_in,
                              void* d_out, int out_size, void* d_ws, size_t ws_size,
                              hipStream_t stream) {
    const float* x = (const float*)d_in[0];
    const float* W = (const float*)d_in[1];
    const float* b = (const float*)d_in[2];
    float* out = (float*)d_out;

    char* ws = (char*)d_ws;
    ushort* xb   = (ushort*)(ws);                       // 32 MB
    ushort* wb   = (ushort*)(ws + (33554432));          // 32 MB
    double* part = (double*)(ws + (67108864));          // 256*4096*8 = 8 MB
    double* xbar = (double*)(ws + (67108864 + 8388608));        // 32 KB
    int*    idx  = (int*)   (ws + (67108864 + 8388608 + 32768)); // 16 KB

    cvt_x_colsum<<<dim3(4, 256), 256, 0, stream>>>(x, xb, part);
    xbar_reduce<<<16, 256, 0, stream>>>(part, xbar);
    cvt_w_means<<<4096, 256, 0, stream>>>(W, b, xbar, wb, idx);
    gemm_bt_act<<<dim3(32, 32), 256, 0, stream>>>(xb, wb, b, idx, out);
}

// Round 3
// 344.440 us; speedup vs baseline: 1.1921x; 1.0620x over previous
//
#include <hip/hip_runtime.h>
#include <hip/hip_bf16.h>
#include <math.h>

#define B_DIM   4096
#define IN_DIM  4096
#define OUT_DIM 4096

typedef __attribute__((ext_vector_type(8))) short  short8;   // 8 x bf16 = 4 VGPRs
typedef __attribute__((ext_vector_type(4))) float  floatx4;  // MFMA 16x16 accum

__device__ __forceinline__ ushort f2bf(float f) {
    unsigned b = __float_as_uint(f);
    return (ushort)((b + 0x7fffu + ((b >> 16) & 1u)) >> 16);   // RNE
}

// ---- fused: x fp32 -> bf16  AND  fp64 partial column sums of x ----
// grid (4, 256): bx -> 1024-col slab (4 cols/thread), by -> 16-row chunk
__global__ void cvt_x_colsum(const float* __restrict__ x, ushort* __restrict__ xb,
                             double* __restrict__ part) {
    int c0 = blockIdx.x * 1024 + threadIdx.x * 4;
    int r0 = blockIdx.y * 16;
    double s0 = 0, s1 = 0, s2 = 0, s3 = 0;
#pragma unroll 4
    for (int r = 0; r < 16; ++r) {
        size_t off = (size_t)(r0 + r) * IN_DIM + c0;
        float4 v = *(const float4*)(x + off);
        ushort4 o;
        o.x = f2bf(v.x); o.y = f2bf(v.y); o.z = f2bf(v.z); o.w = f2bf(v.w);
        *(ushort4*)(xb + off) = o;
        s0 += (double)v.x; s1 += (double)v.y; s2 += (double)v.z; s3 += (double)v.w;
    }
    double* p = part + (size_t)blockIdx.y * IN_DIM + c0;
    p[0] = s0; p[1] = s1; p[2] = s2; p[3] = s3;
}

// ---- fold 256 partial chunks -> xbar = mean(x, axis=0) (fp64), 64 blocks ----
__global__ void xbar_reduce(const double* __restrict__ part, double* __restrict__ xbar) {
    __shared__ double red[256];
    int col   = blockIdx.x * 64 + (threadIdx.x & 63);
    int slice = threadIdx.x >> 6;            // 0..3, 64 partial-chunks each
    double s = 0.0;
    for (int rb = slice * 64; rb < slice * 64 + 64; ++rb)
        s += part[(size_t)rb * IN_DIM + col];
    red[threadIdx.x] = s;
    __syncthreads();
    if (slice == 0) {
        double v = red[threadIdx.x] + red[threadIdx.x + 64]
                 + red[threadIdx.x + 128] + red[threadIdx.x + 192];
        xbar[col] = v * (1.0 / (double)B_DIM);
    }
}

// ---- fused: W fp32 -> bf16  AND  means[o] = dot(xbar,W[o,:]) + b[o] -> idx[o] ----
__global__ void cvt_w_means(const float* __restrict__ W, const float* __restrict__ bias,
                            const double* __restrict__ xbar, ushort* __restrict__ wb,
                            int* __restrict__ idx) {
    __shared__ double red[256];
    int o = blockIdx.x;
    size_t base = (size_t)o * IN_DIM;
    double s = 0.0;
#pragma unroll
    for (int j = 0; j < 4; ++j) {
        int i = j * 1024 + threadIdx.x * 4;
        float4 v = *(const float4*)(W + base + i);
        ushort4 ob;
        ob.x = f2bf(v.x); ob.y = f2bf(v.y); ob.z = f2bf(v.z); ob.w = f2bf(v.w);
        *(ushort4*)(wb + base + i) = ob;
        double2 xv0 = *(const double2*)(xbar + i);
        double2 xv1 = *(const double2*)(xbar + i + 2);
        s += (double)v.x * xv0.x + (double)v.y * xv0.y
           + (double)v.z * xv1.x + (double)v.w * xv1.y;
    }
    red[threadIdx.x] = s;
    __syncthreads();
    for (int st = 128; st > 0; st >>= 1) {
        if (threadIdx.x < st) red[threadIdx.x] += red[threadIdx.x + st];
        __syncthreads();
    }
    if (threadIdx.x == 0) {
        // fp32 mod semantics as in jnp (md==3.0f edge lands in else/sigmoid)
        float mf = (float)(red[0] + (double)bias[o]);
        float md = fmodf(mf, 3.0f);
        if (md < 0.0f) md += 3.0f;
        idx[o] = (int)md;
    }
}

// ---- bf16 MFMA GEMM, BK=64, XOR-swizzled LDS, fused branchless epilogue ----
// 128x128 tile, 256 threads = 4 waves (2x2), each wave 64x64 via 4x4 MFMAs.
// LDS k-block swizzle: physical kb = logical kb ^ (row & 7) -> 2-way bank
// aliasing only (free). Staging permutes 16B granules within a 128B row, so
// global cache-line footprint is unchanged and global_load_lds's
// wave-uniform-base + lane*16 constraint still holds.
__global__ void __launch_bounds__(256) gemm_bt_act(
    const ushort* __restrict__ A,   // [M,K] bf16 bits (x)
    const ushort* __restrict__ Bt,  // [N,K] bf16 bits (W)
    const float*  __restrict__ bias,
    const int*    __restrict__ idx,
    float*        __restrict__ out) {
    __shared__ __align__(16) ushort As[128 * 64];
    __shared__ __align__(16) ushort Bs[128 * 64];

    const int t    = threadIdx.x;
    const int w    = t >> 6;
    const int l    = t & 63;
    const int quad = l >> 4;
    const int lrow = l & 15;

    // 8x8 supertile swizzle over the 32x32 tile grid (LLC locality)
    const int b   = blockIdx.y * 32 + blockIdx.x;
    const int sup = b >> 6;
    const int q   = b & 63;
    const int m0  = ((sup >> 2) * 8 + (q >> 3)) * 128;
    const int n0  = ((sup & 3)  * 8 + (q & 7))  * 128;

    const int m0w  = (w >> 1) * 64;
    const int n0w  = (w & 1) * 64;
    const int K    = IN_DIM;

    floatx4 acc[4][4] = {};

    for (int k0 = 0; k0 < K; k0 += 64) {
#pragma unroll
        for (int j = 0; j < 4; ++j) {
            int chunk = j * 256 + t;                       // 0..1023
            int r     = chunk >> 3;                        // tile row 0..127
            int kb    = (chunk & 7) ^ (r & 7);             // swizzled k-granule
            int goff  = kb << 3;                           // global k offset (elems)
            int ldsoff = (j * 256 + w * 64) * 8;           // wave-uniform base
            __builtin_amdgcn_global_load_lds(
                (__attribute__((address_space(1))) void*)(A + (size_t)(m0 + r) * K + k0 + goff),
                (__attribute__((address_space(3))) void*)(As + ldsoff), 16, 0, 0);
            __builtin_amdgcn_global_load_lds(
                (__attribute__((address_space(1))) void*)(Bt + (size_t)(n0 + r) * K + k0 + goff),
                (__attribute__((address_space(3))) void*)(Bs + ldsoff), 16, 0, 0);
        }
        __syncthreads();

#pragma unroll
        for (int s = 0; s < 2; ++s) {
            short8 af[4], bf[4];
#pragma unroll
            for (int mi = 0; mi < 4; ++mi) {
                int r = m0w + mi * 16 + lrow;
                int kb = (s * 4 + quad) ^ (r & 7);
                af[mi] = *(const short8*)&As[r * 64 + kb * 8];
            }
#pragma unroll
            for (int ni = 0; ni < 4; ++ni) {
                int r = n0w + ni * 16 + lrow;
                int kb = (s * 4 + quad) ^ (r & 7);
                bf[ni] = *(const short8*)&Bs[r * 64 + kb * 8];
            }
#pragma unroll
            for (int mi = 0; mi < 4; ++mi)
#pragma unroll
                for (int ni = 0; ni < 4; ++ni)
                    acc[mi][ni] = __builtin_amdgcn_mfma_f32_16x16x32_bf16(
                        af[mi], bf[ni], acc[mi][ni], 0, 0, 0);
        }
        __syncthreads();
    }

    // epilogue: y = acc + bias[col]; branchless activation by idx[col]
    // C/D mapping: col = lane&15, row = quad*4 + reg
    // relu(y)=max(y,0); sigmoid(y)=rcp(1+exp(-y)); tanh(y)=2*sigmoid(2y)-1
#pragma unroll
    for (int ni = 0; ni < 4; ++ni) {
        int   col     = n0 + n0w + ni * 16 + lrow;
        int   id      = idx[col];
        float bv      = bias[col];
        float a       = (id == 1) ? -2.0f : -1.0f;
        bool  isrelu  = (id == 0);
        bool  istanh  = (id == 1);
#pragma unroll
        for (int mi = 0; mi < 4; ++mi) {
            int rowb = m0 + m0w + mi * 16 + quad * 4;
#pragma unroll
            for (int r = 0; r < 4; ++r) {
                float y   = acc[mi][ni][r] + bv;
                float e   = __expf(a * y);                     // v_exp_f32 path
                float s   = __builtin_amdgcn_rcpf(1.0f + e);   // v_rcp_f32
                float act = istanh ? fmaf(2.0f, s, -1.0f) : s;
                float v   = isrelu ? fmaxf(y, 0.0f) : act;
                out[(size_t)(rowb + r) * OUT_DIM + col] = v;
            }
        }
    }
}

extern "C" void kernel_launch(void* const* d_in, const int* in_sizes, int n_in,
                              void* d_out, int out_size, void* d_ws, size_t ws_size,
                              hipStream_t stream) {
    const float* x = (const float*)d_in[0];
    const float* W = (const float*)d_in[1];
    const float* b = (const float*)d_in[2];
    float* out = (float*)d_out;

    char* ws = (char*)d_ws;
    ushort* xb   = (ushort*)(ws);                       // 32 MB
    ushort* wb   = (ushort*)(ws + (33554432));          // 32 MB
    double* part = (double*)(ws + (67108864));          // 256*4096*8 = 8 MB
    double* xbar = (double*)(ws + (67108864 + 8388608));        // 32 KB
    int*    idx  = (int*)   (ws + (67108864 + 8388608 + 32768)); // 16 KB

    cvt_x_colsum<<<dim3(4, 256), 256, 0, stream>>>(x, xb, part);
    xbar_reduce<<<64, 256, 0, stream>>>(part, xbar);
    cvt_w_means<<<4096, 256, 0, stream>>>(W, b, xbar, wb, idx);
    gemm_bt_act<<<dim3(32, 32), 256, 0, stream>>>(xb, wb, b, idx, out);
}